// Round 5
// baseline (371.333 us; speedup 1.0000x reference)
//
#include <hip/hip_runtime.h>
#include <hip/hip_bf16.h>
#include <stdint.h>
#include <stddef.h>

// Causal single-head attention, B=4 S=2048 D=1024. fp32 in/out; bf16 MFMA inside.
// R12: PROBE ROUND. Five structural variants (R6,R8,R9,R10,R11) all pin QKV at
// 108-110us / ~470 TF across staging engines, buffering depth, vmcnt policy,
// barrier type, tile size, and occupancy 20-35%. All analytic models predict
// 3-10x faster => model wrong, measurement needed. Pipeline reverted to the
// best config (R8, 314.1us) + two probe kernels sized asymmetrically so the
// total-dur delta identifies the wall:
//   probe_mfma  (12.9 GF pure MFMA):      +5us healthy  / +27us wall-rate
//   probe_stage (295 MB gload_lds, L2-hot): +9us healthy / +54us wall-rate
// Bands: ~328 both-healthy | ~350 mfma-wall | ~373 stage-wall | ~395 both.
// Probes write to `out`, fully overwritten by the PV GEMM afterwards.

typedef __hip_bfloat16 bf16;
typedef short short8 __attribute__((ext_vector_type(8)));
typedef short short4v __attribute__((ext_vector_type(4)));
typedef float f32x4 __attribute__((ext_vector_type(4)));

#define BM 128
#define BN 128
#define BK 64
#define MSZ 8192   // B*S
#define DD 1024    // D

__device__ __forceinline__ void cstore(float* p, float v) { *p = v; }
__device__ __forceinline__ void cstore(bf16* p, float v) { *p = __float2bfloat16(v); }

// fp32 -> bf16 downcast, 4 elems/thread
__global__ __launch_bounds__(256)
void f2b(const float* __restrict__ s, bf16* __restrict__ d, int n) {
  const int i = (blockIdx.x * 256 + threadIdx.x) * 4;
  if (i >= n) return;
  const float4 v = *(const float4*)(s + i);
  bf16 t[4] = {__float2bfloat16(v.x), __float2bfloat16(v.y),
               __float2bfloat16(v.z), __float2bfloat16(v.w)};
  *(short4v*)(d + i) = *(short4v*)t;
}

// three weight matrices -> contiguous bf16 block [Wq;Wk;Wv]
__global__ __launch_bounds__(256)
void f2b3(const float* __restrict__ a, const float* __restrict__ b,
          const float* __restrict__ c, bf16* __restrict__ d, int n) {
  const float* s = (blockIdx.y == 0) ? a : (blockIdx.y == 1) ? b : c;
  const int i = (blockIdx.x * 256 + threadIdx.x) * 4;
  if (i >= n) return;
  const float4 v = *(const float4*)(s + i);
  bf16 t[4] = {__float2bfloat16(v.x), __float2bfloat16(v.y),
               __float2bfloat16(v.z), __float2bfloat16(v.w)};
  *(short4v*)(d + (size_t)blockIdx.y * n + i) = *(short4v*)t;
}

// ---------------- PROBES ----------------
// Probe A: pure MFMA throughput, LDS staged once, no loop memory traffic.
// 256 blocks x 4 waves x 768 MFMA x 16384 FLOP = 12.9 GF.
__global__ __launch_bounds__(256, 4)
void probe_mfma(const bf16* __restrict__ src, float* __restrict__ dst) {
  __shared__ short8 As[1024];
  const int tid = threadIdx.x;
  const int wave = tid >> 6, lane = tid & 63;
  const int l15 = lane & 15, q4 = lane >> 4;
  const int sg = lane >> 3, sr = lane & 7;
  const bf16* apg = src + (size_t)(wave * 32 + sr) * 1024 + sg * 8;
  short8* asw = &As[wave * 256];
#pragma unroll
  for (int j = 0; j < 4; j++)
    __builtin_amdgcn_global_load_lds(apg + (size_t)j * 8 * 1024, asw + j * 64, 16, 0, 0);
  __syncthreads();
  const int rh = l15 >> 3, r3 = l15 & 7;
  const int fra = rh * 64 + q4 * 8 + r3;
  short8 af[4], bfr[4];
#pragma unroll
  for (int i = 0; i < 4; i++) af[i] = As[(fra + i * 128) & 1023];
#pragma unroll
  for (int j = 0; j < 4; j++) bfr[j] = As[(fra + 32 + j * 128) & 1023];
  f32x4 acc[4][4] = {};
  for (int t = 0; t < 24; ++t) {
#pragma unroll
    for (int s = 0; s < 2; s++)
#pragma unroll
      for (int i = 0; i < 4; i++)
#pragma unroll
        for (int j = 0; j < 4; j++)
          acc[i][j] = __builtin_amdgcn_mfma_f32_16x16x32_bf16(af[i], bfr[j], acc[i][j], 0, 0, 0);
  }
  float sum = 0.f;
#pragma unroll
  for (int i = 0; i < 4; i++)
#pragma unroll
    for (int j = 0; j < 4; j++)
      sum += acc[i][j][0] + acc[i][j][1] + acc[i][j][2] + acc[i][j][3];
  dst[blockIdx.x * 256 + tid] = sum;  // overwritten by PV later
}

// Probe B: free-running global_load_lds bandwidth, same addressing class as
// the real stage (8 x 1KB wave-insts / 32KB per block-step), L2-resident
// working set (same-class blocks land on the same XCD: (c+32k)%8 == c%8).
// 256 blocks x 36 steps x 32 KB = 295 MB. No barriers in loop -> max MLP.
__global__ __launch_bounds__(256, 4)
void probe_stage(const bf16* __restrict__ src, float* __restrict__ dst) {
  __shared__ short8 LDSb[2][1024];
  const int tid = threadIdx.x;
  const int wave = tid >> 6, lane = tid & 63;
  const int sg = lane >> 3, sr = lane & 7;
  const int bm0 = (int)(blockIdx.x & 31) * 128;
  const bf16* apg = src + (size_t)(bm0 + wave * 32 + sr) * 1024 + sg * 8;
  const bf16* bpg = apg + (size_t)4096 * 1024;
  for (int t = 0; t < 36; ++t) {
    const int k0 = (t & 15) * 64;
    short8* da = &LDSb[t & 1][wave * 256];
#pragma unroll
    for (int j = 0; j < 4; j++) {
      __builtin_amdgcn_global_load_lds(apg + (size_t)j * 8 * 1024 + k0, da + j * 64, 16, 0, 0);
      __builtin_amdgcn_global_load_lds(bpg + (size_t)j * 8 * 1024 + k0, da + j * 64, 16, 0, 0);
    }
  }
  asm volatile("s_waitcnt vmcnt(0)" ::: "memory");
  __syncthreads();
  dst[blockIdx.x * 256 + tid] = __bfloat162float(((const bf16*)&LDSb[0][tid & 1023])[0]);
}
// ---------------- END PROBES ----------------

// C[M,N] = A[M,K] * B[N,K]^T (both K-contiguous), bf16 in.  (verbatim R8)
// MODE 1: QKV — A=xb, B=W_all[3072,1024]; bx<16 -> Q|K contiguous rows,
//         bx>=16 -> V stored transposed into C2[D][MS].
// MODE 2: Sc — compact triangular grid: blockIdx.x = tri index (by,bx).
// MODE 3: PV — float out, K clipped at diagonal, by reversed (long-K first).
template <int MODE, typename CT>
__global__ __launch_bounds__(256, 4)
void gemm_bt(const bf16* __restrict__ A, const bf16* __restrict__ B,
             CT* __restrict__ C, bf16* __restrict__ C2,
             int lda, int ldb, int ldc, int K,
             long sA, long sB, long sC, float scale) {
  int by, bx;
  if (MODE == 2) {
    const int t = blockIdx.x;
    by = (int)((__fsqrt_rn(8.f * (float)t + 1.f) - 1.f) * 0.5f);
    while ((by + 1) * (by + 2) / 2 <= t) by++;
    while (by * (by + 1) / 2 > t) by--;
    bx = t - by * (by + 1) / 2;
  } else if (MODE == 3) {
    by = gridDim.y - 1 - blockIdx.y;  // long-K rows dispatch first
    bx = blockIdx.x;
  } else {
    by = blockIdx.y;
    bx = blockIdx.x;
  }

  __shared__ short8 As[1024];  // 16 KB: [rb 0..15][g 0..7][r8 0..7]
  __shared__ short8 Bs[1024];  // 16 KB

  const int tid = threadIdx.x;
  const int wave = tid >> 6, lane = tid & 63;
  const int wm = wave >> 1, wn = wave & 1;  // 2x2 wave grid, 64x64 each
  const int l15 = lane & 15, q4 = lane >> 4;
  const int bm0 = by * BM, bn0 = bx * BN;

  const bf16* Az = A + (long)blockIdx.z * sA;
  const bf16* Bz = B + (long)blockIdx.z * sB;
  CT* Cz = C + (long)blockIdx.z * sC;

  // staging coords: lane = (g<<3)|r8
  const int sg = lane >> 3, sr = lane & 7;
  const bf16* apg = Az + (size_t)(bm0 + wave * 32 + sr) * lda + sg * 8;
  const bf16* bpg = Bz + (size_t)(bn0 + wave * 32 + sr) * ldb + sg * 8;
  short8* asw = &As[wave * 256];  // 4 rowblocks * 64 short8 per wave
  short8* bsw = &Bs[wave * 256];

  const int Ke = (MODE == 3) ? min(K, (by + 1) * BM) : K;

  // fragment read bases: idx(row,gran) = (row>>3)*64 + gran*8 + (row&7)
  const int rh = l15 >> 3, r3 = l15 & 7;
  const int fra = wm * 512 + rh * 64 + q4 * 8 + r3;
  const int frb = wn * 512 + rh * 64 + q4 * 8 + r3;

  f32x4 acc[4][4] = {};

  for (int k0 = 0; k0 < Ke; k0 += BK) {
#pragma unroll
    for (int j = 0; j < 4; j++) {
      __builtin_amdgcn_global_load_lds(apg + (size_t)j * 8 * lda + k0,
                                       asw + j * 64, 16, 0, 0);
      __builtin_amdgcn_global_load_lds(bpg + (size_t)j * 8 * ldb + k0,
                                       bsw + j * 64, 16, 0, 0);
    }
    __syncthreads();  // drains vmcnt(0): tile resident

#pragma unroll
    for (int s = 0; s < 2; s++) {
      short8 af[4], bfr[4];
#pragma unroll
      for (int i = 0; i < 4; i++) af[i] = As[fra + i * 128 + s * 32];
#pragma unroll
      for (int j = 0; j < 4; j++) bfr[j] = Bs[frb + j * 128 + s * 32];
#pragma unroll
      for (int i = 0; i < 4; i++)
#pragma unroll
        for (int j = 0; j < 4; j++)
          acc[i][j] = __builtin_amdgcn_mfma_f32_16x16x32_bf16(af[i], bfr[j], acc[i][j], 0, 0, 0);
    }
    __syncthreads();  // LDS free for next stage
  }

  // epilogue: C/D layout col=lane&15, row=(lane>>4)*4+reg  [m89/m91 verified]
  if (MODE == 1 && bx >= 16) {
#pragma unroll
    for (int i = 0; i < 4; i++) {
#pragma unroll
      for (int j = 0; j < 4; j++) {
        const int rowb = bm0 + wm * 64 + i * 16 + q4 * 4;
        const int v = (bn0 - 2048) + wn * 64 + j * 16 + l15;
        bf16 t[4] = {__float2bfloat16(acc[i][j][0]), __float2bfloat16(acc[i][j][1]),
                     __float2bfloat16(acc[i][j][2]), __float2bfloat16(acc[i][j][3])};
        *(short4v*)(C2 + (size_t)v * MSZ + rowb) = *(short4v*)t;
      }
    }
    return;
  }

  CT* Cb = Cz;
  int coff = bn0;
  if (MODE == 1) {  // Q|K contiguous: K block sits MS*D after Q
    Cb = Cz + (bx >= 8 ? (size_t)MSZ * DD : 0);
    coff = (bx & 7) * BN;
  }
#pragma unroll
  for (int i = 0; i < 4; i++) {
#pragma unroll
    for (int j = 0; j < 4; j++) {
#pragma unroll
      for (int r = 0; r < 4; r++) {
        const int row = bm0 + wm * 64 + i * 16 + q4 * 4 + r;
        const int col = coff + wn * 64 + j * 16 + l15;
        cstore(&Cb[(size_t)row * ldc + col], acc[i][j][r] * scale);
      }
    }
  }
}

// Single-pass register softmax over the causal prefix; one 256-thr block per
// (q,b) row. Zeros above the diagonal so the PV GEMM needs no masking.
__global__ __launch_bounds__(256)
void softmax_rows(const bf16* __restrict__ Sc, bf16* __restrict__ P, int S) {
  const int q = blockIdx.x, b = blockIdx.y;
  const short8* srow = (const short8*)(Sc + ((size_t)b * S + q) * S);
  short8* prow = (short8*)(P + ((size_t)b * S + q) * S);
  const int len = q + 1;
  const int tid = threadIdx.x;
  const int wave = tid >> 6, lane = tid & 63;
  __shared__ float red[10];

  const short8 raw = srow[tid];
  float v[8];
#pragma unroll
  for (int j = 0; j < 8; j++) {
    const int k = tid * 8 + j;
    const float f = __bfloat162float(((const bf16*)&raw)[j]);
    v[j] = (k < len) ? f : -1e30f;
  }

  float m = v[0];
#pragma unroll
  for (int j = 1; j < 8; j++) m = fmaxf(m, v[j]);
#pragma unroll
  for (int o = 32; o; o >>= 1) m = fmaxf(m, __shfl_down(m, o));
  if (lane == 0) red[wave] = m;
  __syncthreads();
  if (tid == 0) red[8] = fmaxf(fmaxf(red[0], red[1]), fmaxf(red[2], red[3]));
  __syncthreads();
  const float M = red[8];

  float e[8], s = 0.f;
#pragma unroll
  for (int j = 0; j < 8; j++) { e[j] = __expf(v[j] - M); s += e[j]; }
#pragma unroll
  for (int o = 32; o; o >>= 1) s += __shfl_down(s, o);
  if (lane == 0) red[4 + wave] = s;
  __syncthreads();
  if (tid == 0) red[9] = red[4] + red[5] + red[6] + red[7];
  __syncthreads();
  const float inv = 1.f / red[9];

  short8 outp;
#pragma unroll
  for (int j = 0; j < 8; j++) {
    const int k = tid * 8 + j;
    ((bf16*)&outp)[j] = __float2bfloat16((k < len) ? e[j] * inv : 0.f);
  }
  prow[tid] = outp;
}

extern "C" void kernel_launch(void* const* d_in, const int* in_sizes, int n_in,
                              void* d_out, int out_size, void* d_ws, size_t ws_size,
                              hipStream_t stream) {
  const float* x  = (const float*)d_in[0];
  const float* Wq = (const float*)d_in[1];
  const float* Wk = (const float*)d_in[2];
  const float* Wv = (const float*)d_in[3];
  float* out = (float*)d_out;

  const int Bb = 4, S = 2048, D = 1024, MS = Bb * S;  // MS = 8192

  // ws layout; P aliases dead xb/W/Q region (consumed before softmax).
  char* ws = (char*)d_ws;
  bf16* xb = (bf16*)ws;                                          // 16.78 MB
  bf16* wb = (bf16*)(ws + (size_t)MS * D * 2);                   // 6.3 MB
  bf16* Q  = (bf16*)(ws + (size_t)MS * D * 2 + 3u * D * D * 2);  // 16.78 MB
  bf16* Kp = Q + (size_t)MS * D;                                 // 16.78 MB (contig after Q)
  bf16* VT = Kp + (size_t)MS * D;                                // 16.78 MB [D,MS]
  bf16* Sc = VT + (size_t)MS * D;                                // 33.55 MB [B,S,S]
  bf16* P  = (bf16*)ws;                                          // aliases xb/W/Q
  (void)Kp;

  dim3 blk(256);

  f2b<<<dim3(MS * D / 4 / 256), blk, 0, stream>>>(x, xb, MS * D);
  f2b3<<<dim3(D * D / 4 / 256, 3), blk, 0, stream>>>(Wq, Wk, Wv, wb, D * D);

  // ---- probes (results land in `out`, fully overwritten by PV below) ----
  probe_stage<<<dim3(256), blk, 0, stream>>>(xb, out);
  probe_mfma<<<dim3(256), blk, 0, stream>>>(xb, out);

  // QKV fused: [Q|K] rows + V transposed, one dispatch (24x64 blocks)
  gemm_bt<1, bf16><<<dim3(3 * D / BN, MS / BM, 1), blk, 0, stream>>>(
      xb, wb, Q, VT, D, D, D, D, 0, 0, 0, 1.f);
  // Sc = (Q K^T)/32, compact triangular grid: 136 tiles x 4 batches
  gemm_bt<2, bf16><<<dim3(136, 1, Bb), blk, 0, stream>>>(
      Q, Kp, Sc, nullptr, D, D, S, D,
      (long)S * D, (long)S * D, (long)S * S, 0.03125f);
  // P = row-softmax(Sc)
  softmax_rows<<<dim3(S, Bb), blk, 0, stream>>>(Sc, P, S);
  // out = P @ V  (B = VT batch slice, K clipped at diagonal)
  gemm_bt<3, float><<<dim3(D / BN, S / BM, Bb), blk, 0, stream>>>(
      P, VT, out, nullptr, S, MS, D, S,
      (long)S * S, (long)S, (long)S * D, 1.f);
}

// Round 7
// 307.412 us; speedup vs baseline: 1.2079x; 1.2079x over previous
//
#include <hip/hip_runtime.h>
#include <hip/hip_bf16.h>
#include <stdint.h>
#include <stddef.h>

// Causal single-head attention, B=4 S=2048 D=1024. fp32 in/out; bf16 MFMA inside.
// R14 = R13 with the PV decode bug fixed (R13 launched 2048 PV blocks with
// by up to 63 -> OOB writes -> crash; correct work is 512 blocks, by<=15).
// Theory unchanged: R12 probes showed staging is L3-service-bound
// (~5.5-7 TB/s; QKV 786MB/7.3TB/s == measured 108us). XCD-aware decode
// (xcd = flat%8) makes each XCD's staged operands L2-resident:
//   QKV: XCD c owns by-band 8c..8c+7 (A 2MB resident), bx-outer (B panel
//        shared by 8 co-resident blocks).
//   Sc:  XCD pair owns one batch; halves split the tri range.
//   PV:  XCD pair owns one batch; bx-inner (P panel shared), by parity-split
//        descending (long-K first); VT 4MB/batch L2-resident.
// GEMM inner loop identical to verified R8 (best measured, 314.1us).

typedef __hip_bfloat16 bf16;
typedef short short8 __attribute__((ext_vector_type(8)));
typedef short short4v __attribute__((ext_vector_type(4)));
typedef float f32x4 __attribute__((ext_vector_type(4)));

#define BM 128
#define BN 128
#define BK 64
#define MSZ 8192   // B*S
#define DD 1024    // D

__device__ __forceinline__ void cstore(float* p, float v) { *p = v; }
__device__ __forceinline__ void cstore(bf16* p, float v) { *p = __float2bfloat16(v); }

// fp32 -> bf16 downcast, 4 elems/thread
__global__ __launch_bounds__(256)
void f2b(const float* __restrict__ s, bf16* __restrict__ d, int n) {
  const int i = (blockIdx.x * 256 + threadIdx.x) * 4;
  if (i >= n) return;
  const float4 v = *(const float4*)(s + i);
  bf16 t[4] = {__float2bfloat16(v.x), __float2bfloat16(v.y),
               __float2bfloat16(v.z), __float2bfloat16(v.w)};
  *(short4v*)(d + i) = *(short4v*)t;
}

// three weight matrices -> contiguous bf16 block [Wq;Wk;Wv]
__global__ __launch_bounds__(256)
void f2b3(const float* __restrict__ a, const float* __restrict__ b,
          const float* __restrict__ c, bf16* __restrict__ d, int n) {
  const float* s = (blockIdx.y == 0) ? a : (blockIdx.y == 1) ? b : c;
  const int i = (blockIdx.x * 256 + threadIdx.x) * 4;
  if (i >= n) return;
  const float4 v = *(const float4*)(s + i);
  bf16 t[4] = {__float2bfloat16(v.x), __float2bfloat16(v.y),
               __float2bfloat16(v.z), __float2bfloat16(v.w)};
  *(short4v*)(d + (size_t)blockIdx.y * n + i) = *(short4v*)t;
}

// C[M,N] = A[M,K] * B[N,K]^T (both K-contiguous), bf16 in. Inner loop = R8.
// All modes launched 1-D; (by, bx, batch) decoded XCD-aware (see header).
// MODE 1: QKV — A=xb, B=W_all[3072,1024]; bx<16 -> Q|K contiguous rows,
//         bx>=16 -> V stored transposed into C2[D][MS].  1536 blocks.
// MODE 2: Sc — triangular, XCD pair per batch.            544 blocks.
// MODE 3: PV — float out, K clipped at diagonal.          512 blocks.
template <int MODE, typename CT>
__global__ __launch_bounds__(256, 4)
void gemm_bt(const bf16* __restrict__ A, const bf16* __restrict__ B,
             CT* __restrict__ C, bf16* __restrict__ C2,
             int lda, int ldb, int ldc, int K,
             long sA, long sB, long sC, float scale) {
  int by, bx, zb;
  const int flat = blockIdx.x;
  const int c = flat & 7, j = flat >> 3;  // XCD (assumed flat%8 round-robin)
  if (MODE == 1) {
    // 1536 = 8 XCD x (24 bx x 8 by). A-band 2MB L2-resident; bx-outer.
    by = c * 8 + (j & 7);
    bx = j >> 3;
    zb = 0;
  } else if (MODE == 2) {
    // 544 = 8 XCD x 68. XCD pair owns batch; halves split tri range 0..135.
    zb = c >> 1;
    const int t = (c & 1) * 68 + j;
    by = (int)((__fsqrt_rn(8.f * (float)t + 1.f) - 1.f) * 0.5f);
    while ((by + 1) * (by + 2) / 2 <= t) by++;
    while (by * (by + 1) / 2 > t) by--;
    bx = t - by * (by + 1) / 2;
  } else {
    // 512 = 8 XCD x 64 (j = 0..63). XCD pair owns batch; bx-inner (P panel
    // shared), by parity-split descending (long-K first): by in 0..15.
    zb = c >> 1;
    bx = j & 7;
    by = 2 * (7 - (j >> 3)) + (c & 1);
  }

  __shared__ short8 As[1024];  // 16 KB: [rb 0..15][g 0..7][r8 0..7]
  __shared__ short8 Bs[1024];  // 16 KB

  const int tid = threadIdx.x;
  const int wave = tid >> 6, lane = tid & 63;
  const int wm = wave >> 1, wn = wave & 1;  // 2x2 wave grid, 64x64 each
  const int l15 = lane & 15, q4 = lane >> 4;
  const int bm0 = by * BM, bn0 = bx * BN;

  const bf16* Az = A + (long)zb * sA;
  const bf16* Bz = B + (long)zb * sB;
  CT* Cz = C + (long)zb * sC;

  // staging coords: lane = (g<<3)|r8
  const int sg = lane >> 3, sr = lane & 7;
  const bf16* apg = Az + (size_t)(bm0 + wave * 32 + sr) * lda + sg * 8;
  const bf16* bpg = Bz + (size_t)(bn0 + wave * 32 + sr) * ldb + sg * 8;
  short8* asw = &As[wave * 256];  // 4 rowblocks * 64 short8 per wave
  short8* bsw = &Bs[wave * 256];

  const int Ke = (MODE == 3) ? min(K, (by + 1) * BM) : K;

  // fragment read bases: idx(row,gran) = (row>>3)*64 + gran*8 + (row&7)
  const int rh = l15 >> 3, r3 = l15 & 7;
  const int fra = wm * 512 + rh * 64 + q4 * 8 + r3;
  const int frb = wn * 512 + rh * 64 + q4 * 8 + r3;

  f32x4 acc[4][4] = {};

  for (int k0 = 0; k0 < Ke; k0 += BK) {
#pragma unroll
    for (int jj = 0; jj < 4; jj++) {
      __builtin_amdgcn_global_load_lds(apg + (size_t)jj * 8 * lda + k0,
                                       asw + jj * 64, 16, 0, 0);
      __builtin_amdgcn_global_load_lds(bpg + (size_t)jj * 8 * ldb + k0,
                                       bsw + jj * 64, 16, 0, 0);
    }
    __syncthreads();  // drains vmcnt(0): tile resident

#pragma unroll
    for (int s = 0; s < 2; s++) {
      short8 af[4], bfr[4];
#pragma unroll
      for (int i = 0; i < 4; i++) af[i] = As[fra + i * 128 + s * 32];
#pragma unroll
      for (int jj = 0; jj < 4; jj++) bfr[jj] = Bs[frb + jj * 128 + s * 32];
#pragma unroll
      for (int i = 0; i < 4; i++)
#pragma unroll
        for (int jj = 0; jj < 4; jj++)
          acc[i][jj] = __builtin_amdgcn_mfma_f32_16x16x32_bf16(af[i], bfr[jj], acc[i][jj], 0, 0, 0);
    }
    __syncthreads();  // LDS free for next stage
  }

  // epilogue: C/D layout col=lane&15, row=(lane>>4)*4+reg  [m89/m91 verified]
  if (MODE == 1 && bx >= 16) {
    // V block: write transposed into C2[D][MS]; pack r=0..3 (consec rows) 8 B
#pragma unroll
    for (int i = 0; i < 4; i++) {
#pragma unroll
      for (int jj = 0; jj < 4; jj++) {
        const int rowb = bm0 + wm * 64 + i * 16 + q4 * 4;
        const int v = (bn0 - 2048) + wn * 64 + jj * 16 + l15;
        bf16 t[4] = {__float2bfloat16(acc[i][jj][0]), __float2bfloat16(acc[i][jj][1]),
                     __float2bfloat16(acc[i][jj][2]), __float2bfloat16(acc[i][jj][3])};
        *(short4v*)(C2 + (size_t)v * MSZ + rowb) = *(short4v*)t;
      }
    }
    return;
  }

  CT* Cb = Cz;
  int coff = bn0;
  if (MODE == 1) {  // Q|K contiguous: K block sits MS*D after Q
    Cb = Cz + (bx >= 8 ? (size_t)MSZ * DD : 0);
    coff = (bx & 7) * BN;
  }
#pragma unroll
  for (int i = 0; i < 4; i++) {
#pragma unroll
    for (int jj = 0; jj < 4; jj++) {
#pragma unroll
      for (int r = 0; r < 4; r++) {
        const int row = bm0 + wm * 64 + i * 16 + q4 * 4 + r;
        const int col = coff + wn * 64 + jj * 16 + l15;
        cstore(&Cb[(size_t)row * ldc + col], acc[i][jj][r] * scale);
      }
    }
  }
}

// Single-pass register softmax over the causal prefix; one 256-thr block per
// (q,b) row. Zeros above the diagonal so the PV GEMM needs no masking.
__global__ __launch_bounds__(256)
void softmax_rows(const bf16* __restrict__ Sc, bf16* __restrict__ P, int S) {
  const int q = blockIdx.x, b = blockIdx.y;
  const short8* srow = (const short8*)(Sc + ((size_t)b * S + q) * S);
  short8* prow = (short8*)(P + ((size_t)b * S + q) * S);
  const int len = q + 1;
  const int tid = threadIdx.x;
  const int wave = tid >> 6, lane = tid & 63;
  __shared__ float red[10];

  const short8 raw = srow[tid];
  float v[8];
#pragma unroll
  for (int j = 0; j < 8; j++) {
    const int k = tid * 8 + j;
    const float f = __bfloat162float(((const bf16*)&raw)[j]);
    v[j] = (k < len) ? f : -1e30f;
  }

  float m = v[0];
#pragma unroll
  for (int j = 1; j < 8; j++) m = fmaxf(m, v[j]);
#pragma unroll
  for (int o = 32; o; o >>= 1) m = fmaxf(m, __shfl_down(m, o));
  if (lane == 0) red[wave] = m;
  __syncthreads();
  if (tid == 0) red[8] = fmaxf(fmaxf(red[0], red[1]), fmaxf(red[2], red[3]));
  __syncthreads();
  const float M = red[8];

  float e[8], s = 0.f;
#pragma unroll
  for (int j = 0; j < 8; j++) { e[j] = __expf(v[j] - M); s += e[j]; }
#pragma unroll
  for (int o = 32; o; o >>= 1) s += __shfl_down(s, o);
  if (lane == 0) red[4 + wave] = s;
  __syncthreads();
  if (tid == 0) red[9] = red[4] + red[5] + red[6] + red[7];
  __syncthreads();
  const float inv = 1.f / red[9];

  short8 outp;
#pragma unroll
  for (int j = 0; j < 8; j++) {
    const int k = tid * 8 + j;
    ((bf16*)&outp)[j] = __float2bfloat16((k < len) ? e[j] * inv : 0.f);
  }
  prow[tid] = outp;
}

extern "C" void kernel_launch(void* const* d_in, const int* in_sizes, int n_in,
                              void* d_out, int out_size, void* d_ws, size_t ws_size,
                              hipStream_t stream) {
  const float* x  = (const float*)d_in[0];
  const float* Wq = (const float*)d_in[1];
  const float* Wk = (const float*)d_in[2];
  const float* Wv = (const float*)d_in[3];
  float* out = (float*)d_out;

  const int Bb = 4, S = 2048, D = 1024, MS = Bb * S;  // MS = 8192

  // ws layout; P aliases dead xb/W/Q region (consumed before softmax).
  char* ws = (char*)d_ws;
  bf16* xb = (bf16*)ws;                                          // 16.78 MB
  bf16* wb = (bf16*)(ws + (size_t)MS * D * 2);                   // 6.3 MB
  bf16* Q  = (bf16*)(ws + (size_t)MS * D * 2 + 3u * D * D * 2);  // 16.78 MB
  bf16* Kp = Q + (size_t)MS * D;                                 // 16.78 MB (contig after Q)
  bf16* VT = Kp + (size_t)MS * D;                                // 16.78 MB [D,MS]
  bf16* Sc = VT + (size_t)MS * D;                                // 33.55 MB [B,S,S]
  bf16* P  = (bf16*)ws;                                          // aliases xb/W/Q
  (void)Kp;

  dim3 blk(256);

  f2b<<<dim3(MS * D / 4 / 256), blk, 0, stream>>>(x, xb, MS * D);
  f2b3<<<dim3(D * D / 4 / 256, 3), blk, 0, stream>>>(Wq, Wk, Wv, wb, D * D);

  // QKV fused: [Q|K] rows + V transposed (1536 blocks, XCD-chunked decode)
  gemm_bt<1, bf16><<<dim3(1536), blk, 0, stream>>>(
      xb, wb, Q, VT, D, D, D, D, 0, 0, 0, 1.f);
  // Sc = (Q K^T)/32, triangular (544 blocks: XCD pair per batch)
  gemm_bt<2, bf16><<<dim3(544), blk, 0, stream>>>(
      Q, Kp, Sc, nullptr, D, D, S, D,
      (long)S * D, (long)S * D, (long)S * S, 0.03125f);
  // P = row-softmax(Sc)
  softmax_rows<<<dim3(S, Bb), blk, 0, stream>>>(Sc, P, S);
  // out = P @ V  (512 blocks: XCD pair per batch, K clipped at diagonal)
  gemm_bt<3, float><<<dim3(512), blk, 0, stream>>>(
      P, VT, out, nullptr, S, MS, D, S,
      (long)S * S, (long)S, (long)S * D, 1.f);
}